// Round 9
// baseline (311.250 us; speedup 1.0000x reference)
//
#include <hip/hip_runtime.h>
#include <hip/hip_bf16.h>

#define Qn 2048
#define Kn 2048
#define Cin 128
#define Hn 8
#define CHn 32
#define HDn 256
#define NSPLIT 8

typedef __attribute__((ext_vector_type(8))) short short8;
typedef __attribute__((ext_vector_type(4))) float f32x4;
typedef __attribute__((ext_vector_type(8))) _Float16 f16x8;

static __device__ __forceinline__ unsigned short f2bf(float f) {
    unsigned int u = __float_as_uint(f);
    u += 0x7fffu + ((u >> 16) & 1u);
    return (unsigned short)(u >> 16);
}

// ---------------------------------------------------------------------------
// K0: prep. Pure streaming pass: pdb = fp16(dist + bias) in the exact
// per-lane MFMA C-layout gather order attn consumes:
//   pdb[((qt*32 + ktg)*8 + h)*1024 + l*16 + (kkg*4 + r)]
//     = dist[qt*16 + (l>>4)*4 + r][ktg*64 + kkg*16 + (l&15)][h] + bias[...]
// Block (qt, G=quarter of 4 q-rows, kc=256-k chunk): reads 4 rows x 256 k x
// 8 h f32 fully coalesced (4KB/instr/block), LDS-transposes, writes 16 KB
// in 512 B contiguous runs. Reads dist ONCE as a clean 6TB/s-class stream —
// this kernel is the decisive test of the "fused streaming caps at 2TB/s"
// theory. fp16(dist+bias) is the numeric path that passes @3.05e-5.
// ---------------------------------------------------------------------------
__global__ __launch_bounds__(256) void prep_kernel(
    const float* __restrict__ bias, const float* __restrict__ dist,
    _Float16* __restrict__ pdb)
{
    __shared__ _Float16 lds[10240]; // 8192 halves + stride-8 pad (20 KB)
    const int b = blockIdx.x;
    const int kc = b & 7;
    const int G = (b >> 3) & 3;
    const int qt = b >> 5;
    const int t = threadIdx.x;
    const int q0 = qt * 16 + G * 4;
    const int k0 = kc * 256;

    #pragma unroll
    for (int i = 0; i < 8; ++i) {
        const int idx = i * 1024 + t * 4;          // flat over [qr(4)][k_l(256)][h(8)]
        const int qr = idx >> 11;
        const int k_l = (idx >> 3) & 255;
        const int h0 = idx & 7;                    // 0 or 4
        const f32x4 v = *(const f32x4*)(dist + ((size_t)(q0 + qr) * Kn + k0 + k_l) * 8 + h0);
        const float bb = bias[(size_t)(q0 + qr) * Kn + k0 + k_l];
        const int n = k_l & 15;
        const int kkg = (k_l >> 4) & 3;
        const int ktl = k_l >> 6;
        #pragma unroll
        for (int j = 0; j < 4; ++j) {
            const int f = ((h0 + j) * 4 + ktl) * 256 + n * 16 + kkg * 4 + qr;
            lds[f + (f >> 5) * 8] = (_Float16)(v[j] + bb);
        }
    }
    __syncthreads();
    // thread t owns halves f in [t*32, t*32+32) -> padded run [t*40, t*40+32)
    const int h = t >> 5;
    const int ktl = (t >> 3) & 3;
    const int nn = (t & 7) * 2;
    _Float16* dst = pdb + (((size_t)(qt * 32 + kc * 4 + ktl) * 8 + h) << 10) + G * 256 + nn * 16;
    const _Float16* src = lds + t * 40;
    #pragma unroll
    for (int i = 0; i < 4; ++i)
        *(short8*)(dst + i * 8) = *(const short8*)(src + i * 8);
}

// ---------------------------------------------------------------------------
// K1: projections. q=(qx@Wq)/sqrt(CH)->bf16 [Q][HD]; k=kvx@Wk->bf16 [K][HD];
//     v=kvx@Wv->bf16 TRANSPOSED [HD][K]; g=sigmoid(qx@Wg+bg)->f32 [Q][HD].
// ---------------------------------------------------------------------------
__global__ __launch_bounds__(256) void proj_kernel(
    const float* __restrict__ qx, const float* __restrict__ kvx,
    const float* __restrict__ Wq, const float* __restrict__ Wk,
    const float* __restrict__ Wv, const float* __restrict__ Wg,
    const float* __restrict__ bg,
    unsigned short* __restrict__ qb, unsigned short* __restrict__ kb,
    unsigned short* __restrict__ vtb, float* __restrict__ gb)
{
    const int mat = blockIdx.y;
    const int r0 = blockIdx.x * 8;
    const int j = threadIdx.x;
    const float* A = (mat == 0 || mat == 3) ? qx : kvx;
    const float* W = (mat == 0) ? Wq : (mat == 1) ? Wk : (mat == 2) ? Wv : Wg;
    const float* Ar = A + r0 * Cin;
    float acc[8] = {0.f, 0.f, 0.f, 0.f, 0.f, 0.f, 0.f, 0.f};
    for (int c = 0; c < Cin; ++c) {
        const float w = W[c * HDn + j];
        #pragma unroll
        for (int i = 0; i < 8; ++i)
            acc[i] = fmaf(Ar[i * Cin + c], w, acc[i]);
    }
    if (mat == 0) {
        const float s = 0.17677669529663687f; // 1/sqrt(32)
        #pragma unroll
        for (int i = 0; i < 8; ++i)
            qb[(r0 + i) * HDn + j] = f2bf(acc[i] * s);
    } else if (mat == 1) {
        #pragma unroll
        for (int i = 0; i < 8; ++i)
            kb[(r0 + i) * HDn + j] = f2bf(acc[i]);
    } else if (mat == 2) {
        unsigned short tmp[8];
        #pragma unroll
        for (int i = 0; i < 8; ++i) tmp[i] = f2bf(acc[i]);
        *(short8*)(vtb + (size_t)j * Kn + r0) = *(short8*)tmp;
    } else {
        const float b = bg[j];
        #pragma unroll
        for (int i = 0; i < 8; ++i)
            gb[(r0 + i) * HDn + j] = 1.f / (1.f + __expf(-(acc[i] + b)));
    }
}

// ---------------------------------------------------------------------------
// K2: fused attention. Grid 1024 = 128 q-tiles x 8 K-splits, 512 thr = 8 waves
// (wave == head). KVB=64, 4 tiles/block. BARRIER-FREE: dist/bias arrive via
// pdb (prep's fp16 gathered layout) as TWO contiguous 32B loads per lane per
// tile — no dist LDS, no staging, no __syncthreads (ps is wave-local). Each
// block reads a contiguous 64 KB pdb region, L3-hot from prep. KV from L2.
// 16 free-running waves/CU hide everything via TLP.
// R8 bug fixed: ps row stride must be >= 64 halves for KVB=64 (was 40,
// rows overlapped by 24 -> P corruption, absmax 6e-3). Now 72 (R0/R1 layout).
// No-max softmax safe: |logit| < 8.
// ---------------------------------------------------------------------------
__global__ __launch_bounds__(512, 4) void attn_kernel(
    const unsigned short* __restrict__ qb, const unsigned short* __restrict__ kb,
    const unsigned short* __restrict__ vtb, const _Float16* __restrict__ pdb,
    float* __restrict__ opart, float* __restrict__ lpart)
{
    __shared__ unsigned short ps[Hn][16][72]; // 18.4 KB, P round-trip (wave-local)

    const int bx = blockIdx.x;
    const int qt = bx >> 3;
    const int sp = bx & 7;
    const int q0 = qt * 16;
    const int k00 = sp * 256;
    const int t = threadIdx.x;
    const int h = t >> 6;   // wave id == head
    const int l = t & 63;
    const int g = l >> 4;
    const int n = l & 15;

    const short8 qf = *(const short8*)(qb + (q0 + n) * HDn + h * CHn + g * 8);

    f32x4 o0 = {0.f, 0.f, 0.f, 0.f};
    f32x4 o1 = {0.f, 0.f, 0.f, 0.f};
    float lacc[4] = {0.f, 0.f, 0.f, 0.f};
    unsigned short* psh = &ps[h][0][0];
    const f32x4 z = {0.f, 0.f, 0.f, 0.f};

    // per-wave pdb base: tile ktg = sp*4 + kt, lane chunk l*16 halves
    const _Float16* pbase = pdb + ((((size_t)qt * 32 + sp * 4) * 8 + h) << 10) + (l << 4);

    #pragma unroll
    for (int kt = 0; kt < 4; ++kt) {
        const int k0 = k00 + kt * 64;

        short8 kf[4];
        #pragma unroll
        for (int kkg = 0; kkg < 4; ++kkg)
            kf[kkg] = *(const short8*)(kb + (k0 + kkg * 16 + n) * HDn + h * CHn + g * 8);
        short8 vf[2][2];
        #pragma unroll
        for (int c = 0; c < 2; ++c) {
            vf[c][0] = *(const short8*)(vtb + (h * CHn + n) * Kn + k0 + c * 32 + g * 8);
            vf[c][1] = *(const short8*)(vtb + (h * CHn + 16 + n) * Kn + k0 + c * 32 + g * 8);
        }
        // dist+bias, pre-gathered: 32 B/lane
        const f16x8 pa = *(const f16x8*)(pbase + (kt << 13));
        const f16x8 pb = *(const f16x8*)(pbase + (kt << 13) + 8);

        // QK^T
        f32x4 sf[4];
        #pragma unroll
        for (int kkg = 0; kkg < 4; ++kkg)
            sf[kkg] = __builtin_amdgcn_mfma_f32_16x16x32_bf16(qf, kf[kkg], z, 0, 0, 0);

        // p = exp(s + pdb); row sums; P -> LDS bf16 (wave-local, no barrier)
        #pragma unroll
        for (int kkg = 0; kkg < 4; ++kkg) {
            #pragma unroll
            for (int r = 0; r < 4; ++r) {
                const int j = kkg * 4 + r;
                const float dv = (float)((j < 8) ? pa[j & 7] : pb[j & 7]);
                const float p = __expf(sf[kkg][r] + dv);
                sf[kkg][r] = p;
                lacc[r] += p;
                psh[(g * 4 + r) * 72 + kkg * 16 + n] = f2bf(p);
            }
        }

        // PV
        #pragma unroll
        for (int c = 0; c < 2; ++c) {
            const short8 pf = *(const short8*)(psh + n * 72 + c * 32 + g * 8);
            o0 = __builtin_amdgcn_mfma_f32_16x16x32_bf16(pf, vf[c][0], o0, 0, 0, 0);
            o1 = __builtin_amdgcn_mfma_f32_16x16x32_bf16(pf, vf[c][1], o1, 0, 0, 0);
        }
    }

    // write partial O and row-sums
    float* op = opart + (size_t)sp * (Qn * HDn);
    #pragma unroll
    for (int r = 0; r < 4; ++r) {
        const int qg = q0 + g * 4 + r;
        op[qg * HDn + h * CHn + n] = o0[r];
        op[qg * HDn + h * CHn + 16 + n] = o1[r];
        float v = lacc[r];
        v += __shfl_xor(v, 1);
        v += __shfl_xor(v, 2);
        v += __shfl_xor(v, 4);
        v += __shfl_xor(v, 8);
        lacc[r] = v;
    }
    if (n == 0) {
        float* lp = lpart + (size_t)sp * (Qn * Hn);
        #pragma unroll
        for (int r = 0; r < 4; ++r)
            lp[(q0 + g * 4 + r) * Hn + h] = lacc[r];
    }
}

// ---------------------------------------------------------------------------
// K3: merge splits + gating + output projection. One block per q-row.
// ---------------------------------------------------------------------------
__global__ __launch_bounds__(256) void mergeout_kernel(
    const float* __restrict__ opart, const float* __restrict__ lpart,
    const float* __restrict__ gb, const float* __restrict__ Wo,
    const float* __restrict__ bo, float* __restrict__ out)
{
    __shared__ float olds[HDn];
    __shared__ float red[4][128];
    const int q = blockIdx.x;
    const int t = threadIdx.x;
    const int h = t >> 5;
    float s = 0.f;
    #pragma unroll
    for (int sp = 0; sp < NSPLIT; ++sp)
        s += opart[(size_t)sp * (Qn * HDn) + q * HDn + t];
    float lt = 0.f;
    #pragma unroll
    for (int sp = 0; sp < NSPLIT; ++sp)
        lt += lpart[(size_t)sp * (Qn * Hn) + q * Hn + h];
    olds[t] = (s / lt) * gb[q * HDn + t];
    __syncthreads();
    const int p = t & 63;
    const int seg = t >> 6;
    float a0 = 0.f, a1 = 0.f;
    for (int c = seg * 64; c < seg * 64 + 64; ++c) {
        const float ov = olds[c];
        const float2 w = *(const float2*)(Wo + c * Cin + 2 * p);
        a0 = fmaf(ov, w.x, a0);
        a1 = fmaf(ov, w.y, a1);
    }
    red[seg][2 * p] = a0;
    red[seg][2 * p + 1] = a1;
    __syncthreads();
    if (t < 128)
        out[q * Cin + t] = red[0][t] + red[1][t] + red[2][t] + red[3][t] + bo[t];
}

extern "C" void kernel_launch(void* const* d_in, const int* in_sizes, int n_in,
                              void* d_out, int out_size, void* d_ws, size_t ws_size,
                              hipStream_t stream)
{
    const float* qx   = (const float*)d_in[0];
    const float* kvx  = (const float*)d_in[1];
    const float* bias = (const float*)d_in[2];
    const float* dist = (const float*)d_in[3];
    const float* Wq   = (const float*)d_in[4];
    const float* Wk   = (const float*)d_in[5];
    const float* Wv   = (const float*)d_in[6];
    const float* Wg   = (const float*)d_in[7];
    const float* bg   = (const float*)d_in[8];
    const float* Wo   = (const float*)d_in[9];
    const float* bo   = (const float*)d_in[10];
    float* out = (float*)d_out;

    char* w = (char*)d_ws;
    unsigned short* qb  = (unsigned short*)(w);                  // 1 MB
    unsigned short* kb  = (unsigned short*)(w + (1ull << 20));   // 1 MB
    unsigned short* vtb = (unsigned short*)(w + (2ull << 20));   // 1 MB
    float* gb    = (float*)(w + (3ull << 20));                   // 2 MB
    float* opart = (float*)(w + (5ull << 20));                   // 16 MB (8 splits)
    float* lpart = (float*)(w + (21ull << 20));                  // 512 KB
    _Float16* pdb = (_Float16*)(w + (24ull << 20));              // 64 MB

    prep_kernel<<<dim3(4096), 256, 0, stream>>>(bias, dist, pdb);
    proj_kernel<<<dim3(Qn / 8, 4), 256, 0, stream>>>(qx, kvx, Wq, Wk, Wv, Wg, bg, qb, kb, vtb, gb);
    attn_kernel<<<dim3(128 * NSPLIT), 512, 0, stream>>>(qb, kb, vtb, pdb, opart, lpart);
    mergeout_kernel<<<dim3(Qn), 256, 0, stream>>>(opart, lpart, gb, Wo, bo, out);
}